// Round 1
// baseline (1912.548 us; speedup 1.0000x reference)
//
#include <hip/hip_runtime.h>

// IndexAddInplace: out = x.at[idx].add(src)
//   x   : (100000, 512) f32
//   idx : (200000,)     int32 (harness passes integers as int)
//   src : (200000, 512) f32
// Duplicate indices accumulate -> hardware fp32 global atomics.

#define D        512
#define D_VEC4   128          // 512 / 4
#define N_DST    100000
#define N_SRC    200000

// Kernel A: out = x  (full copy every launch; harness poisons d_out)
__global__ void IndexAdd_copy_kernel(const float4* __restrict__ x,
                                     float4* __restrict__ out, int n4) {
    int i = blockIdx.x * blockDim.x + threadIdx.x;
    if (i < n4) out[i] = x[i];
}

// Kernel B: out[idx[r]] += src[r], one float4 per thread, 128 threads/row.
__global__ void IndexAdd_scatter_kernel(const float* __restrict__ src,
                                        const int* __restrict__ idx,
                                        float* __restrict__ out) {
    long long t   = (long long)blockIdx.x * blockDim.x + threadIdx.x;
    int       row = (int)(t >> 7);     // / 128
    int       c4  = (int)(t & 127);    // vec4 index within row
    if (row >= N_SRC) return;

    int dst = idx[row];                // broadcast within wave halves; L1-cached
    float4 s = ((const float4*)(src + (long long)row * D))[c4];
    float* o = out + (long long)dst * D + (c4 << 2);

    // unsafeAtomicAdd -> global_atomic_add_f32 (HW fp32 atomic, no CAS loop)
    unsafeAtomicAdd(o + 0, s.x);
    unsafeAtomicAdd(o + 1, s.y);
    unsafeAtomicAdd(o + 2, s.z);
    unsafeAtomicAdd(o + 3, s.w);
}

extern "C" void kernel_launch(void* const* d_in, const int* in_sizes, int n_in,
                              void* d_out, int out_size, void* d_ws, size_t ws_size,
                              hipStream_t stream) {
    const float* x   = (const float*)d_in[0];
    const int*   idx = (const int*)  d_in[1];
    const float* src = (const float*)d_in[2];
    float*       out = (float*)d_out;

    // Kernel A: copy x -> out (float4 vectorized)
    {
        int n4      = N_DST * D_VEC4;           // 12.8M float4
        int threads = 256;
        int blocks  = (n4 + threads - 1) / threads;   // 50000
        IndexAdd_copy_kernel<<<blocks, threads, 0, stream>>>(
            (const float4*)x, (float4*)out, n4);
    }

    // Kernel B: scatter-add src into out (ordered after A on same stream)
    {
        long long total  = (long long)N_SRC * D_VEC4; // 25.6M threads
        int       threads = 256;
        int       blocks  = (int)((total + threads - 1) / threads); // 100000
        IndexAdd_scatter_kernel<<<blocks, threads, 0, stream>>>(src, idx, out);
    }
}